// Round 1
// baseline (1368.159 us; speedup 1.0000x reference)
//
#include <hip/hip_runtime.h>

// LSTM: B=2048, T=1024, H=50, input_size=1.
// Strategy: 1 workgroup (256 thr) owns BW=4 batch chains end-to-end.
//   Dot phase : thread g (<200) holds W_hh row in 50 VGPRs, accumulates the
//               gate preact for 4 batches; h broadcast from LDS via float4.
//   Epilogue  : thread (j,b) (<200) applies sigmoid/tanh, keeps c in a reg,
//               writes new h to LDS.
// Per-step sync: 2 __syncthreads (workgroup-local only; batches independent).

#define H  50
#define G  200      // 4*H, PyTorch gate order i,f,g,o
#define TT 1024
#define BATCH 2048
#define BW 4        // batches per workgroup
#define TC 16       // x-chunk (timesteps staged in LDS per global load round)

__device__ __forceinline__ float fast_sigmoid(float x) {
    // 1/(1+exp(-x)) ; exp(-x) = exp2(-x*log2e). Saturates correctly at +-inf.
    float e = __builtin_amdgcn_exp2f(-1.4426950408889634f * x);
    return __builtin_amdgcn_rcpf(1.0f + e);
}
__device__ __forceinline__ float fast_tanh(float x) {
    // 1 - 2/(exp(2x)+1) ; exp(2x) = exp2(x*2*log2e). Saturates to +-1.
    float e = __builtin_amdgcn_exp2f(2.8853900817779268f * x);
    return 1.0f - 2.0f * __builtin_amdgcn_rcpf(e + 1.0f);
}

__global__ __launch_bounds__(256, 2) void lstm_kernel(
    const float* __restrict__ x,      // [B, T]
    const float* __restrict__ W_ih,   // [200] (input size 1)
    const float* __restrict__ W_hh,   // [200, 50] row-major
    const float* __restrict__ b_ih,   // [200]
    const float* __restrict__ b_hh,   // [200]
    const float* __restrict__ W_lin,  // [50]
    const float* __restrict__ b_lin,  // [1]
    float* __restrict__ out)          // [B]
{
    __shared__ float h_lds[H][BW];      // [50][4], 16B rows -> float4 broadcast
    __shared__ float gate_lds[G][BW];   // [200][4]
    __shared__ float xs[BW][TC];        // staged x chunk

    const int tid = threadIdx.x;
    const int b0  = blockIdx.x * BW;

    // ---- one-time: W_hh row -> VGPRs ----
    float Wr[H];
    float wih = 0.f, bias = 0.f;
    if (tid < G) {
        #pragma unroll
        for (int k = 0; k < H; ++k) Wr[k] = W_hh[tid * H + k];
        wih  = W_ih[tid];
        bias = b_ih[tid] + b_hh[tid];
    }
    if (tid < H) {
        #pragma unroll
        for (int b = 0; b < BW; ++b) h_lds[tid][b] = 0.f;
    }
    float c = 0.f;                 // cell state of epilogue thread (j, eb)
    const int j  = tid % H;
    const int eb = tid / H;
    __syncthreads();

    for (int t = 0; t < TT; ++t) {
        const int tc = t & (TC - 1);
        if (tc == 0) {
            // previous iteration's closing barrier guarantees old xs reads done
            if (tid < BW * TC) {
                int bb = tid / TC, cc = tid % TC;
                xs[bb][cc] = x[(size_t)(b0 + bb) * TT + t + cc];
            }
            __syncthreads();
        }

        // ---- dot phase: gate preactivations for 4 batches ----
        if (tid < G) {
            float acc0 = __builtin_fmaf(wih, xs[0][tc], bias);
            float acc1 = __builtin_fmaf(wih, xs[1][tc], bias);
            float acc2 = __builtin_fmaf(wih, xs[2][tc], bias);
            float acc3 = __builtin_fmaf(wih, xs[3][tc], bias);
            #pragma unroll
            for (int k = 0; k < H; ++k) {
                float4 hv = *(const float4*)(&h_lds[k][0]);   // wave broadcast
                acc0 = __builtin_fmaf(Wr[k], hv.x, acc0);
                acc1 = __builtin_fmaf(Wr[k], hv.y, acc1);
                acc2 = __builtin_fmaf(Wr[k], hv.z, acc2);
                acc3 = __builtin_fmaf(Wr[k], hv.w, acc3);
            }
            float4 g4 = make_float4(acc0, acc1, acc2, acc3);
            *(float4*)(&gate_lds[tid][0]) = g4;
        }
        __syncthreads();   // gates visible; all h reads complete

        // ---- epilogue: activations + state update for unit j, batch eb ----
        if (tid < H * BW) {
            float gi = gate_lds[j        ][eb];
            float gf = gate_lds[j +   H  ][eb];
            float gg = gate_lds[j + 2*H  ][eb];
            float go = gate_lds[j + 3*H  ][eb];
            float i_ = fast_sigmoid(gi);
            float f_ = fast_sigmoid(gf);
            float g_ = fast_tanh(gg);
            float o_ = fast_sigmoid(go);
            c = __builtin_fmaf(f_, c, i_ * g_);
            h_lds[j][eb] = o_ * fast_tanh(c);
        }
        __syncthreads();   // new h visible for next dot phase
    }

    // ---- head: out[b] = h_last . W_lin + b_lin ----
    if (tid < BW) {
        float s = b_lin[0];
        #pragma unroll
        for (int k = 0; k < H; ++k) s = __builtin_fmaf(h_lds[k][tid], W_lin[k], s);
        out[b0 + tid] = s;
    }
}

extern "C" void kernel_launch(void* const* d_in, const int* in_sizes, int n_in,
                              void* d_out, int out_size, void* d_ws, size_t ws_size,
                              hipStream_t stream) {
    const float* x     = (const float*)d_in[0];
    const float* W_ih  = (const float*)d_in[1];
    const float* W_hh  = (const float*)d_in[2];
    const float* b_ih  = (const float*)d_in[3];
    const float* b_hh  = (const float*)d_in[4];
    const float* W_lin = (const float*)d_in[5];
    const float* b_lin = (const float*)d_in[6];
    float* out = (float*)d_out;

    dim3 grid(BATCH / BW);   // 512 workgroups, 4 batch chains each
    dim3 block(256);
    lstm_kernel<<<grid, block, 0, stream>>>(x, W_ih, W_hh, b_ih, b_hh,
                                            W_lin, b_lin, out);
}

// Round 2
// 1104.719 us; speedup vs baseline: 1.2385x; 1.2385x over previous
//
#include <hip/hip_runtime.h>

// LSTM B=2048, T=1024, H=50 via per-step MFMA.
// Block = 256 thr (4 waves) owns BW=16 batch chains for all 1024 steps.
// W_hh^T lives in B-fragments (f16 hi+lo) in VGPRs, loaded once.
// Per step: h (f16 hi/lo, A-frag layout) read from LDS -> 6 MFMAs per N-tile
// (13 tiles of 16 gates over 4 waves) -> gates to LDS -> epilogue threads
// (unit j, batch b) add exact fp32 x/bias contribution, activations, keep c
// in regs, write new h (f16 hi/lo) back to LDS in A-frag order.
// Numerics: Whi*(hhi+hlo) + Wlo*hhi ~= full fp32 matvec (err ~1e-6/step).

#define H    50
#define TT   1024
#define BATCH 2048
#define BW   16     // batches per block = MFMA M
#define NT   13     // ceil(200/16) N-tiles
#define TC   16     // x timestep chunk staged in LDS
#define GPAD 20     // gate_lds floats per n-row (16 used + 4 pad -> 2-way banks)

typedef float    f32x4 __attribute__((ext_vector_type(4)));
typedef _Float16 f16x8 __attribute__((ext_vector_type(8)));

__device__ __forceinline__ float fast_sigmoid(float x) {
    float e = __builtin_amdgcn_exp2f(-1.4426950408889634f * x);
    return __builtin_amdgcn_rcpf(1.0f + e);
}
__device__ __forceinline__ float fast_tanh(float x) {
    float e = __builtin_amdgcn_exp2f(2.8853900817779268f * x);
    return 1.0f - 2.0f * __builtin_amdgcn_rcpf(e + 1.0f);
}

__global__ __launch_bounds__(256, 1) void lstm_kernel(
    const float* __restrict__ x,      // [B, T]
    const float* __restrict__ W_ih,   // [200]
    const float* __restrict__ W_hh,   // [200, 50]
    const float* __restrict__ b_ih,   // [200]
    const float* __restrict__ b_hh,   // [200]
    const float* __restrict__ W_lin,  // [50]
    const float* __restrict__ b_lin,  // [1]
    float* __restrict__ out)          // [B]
{
    // A-stage: h as f16 in A-frag order. flat idx [kc<8][m<16][e<8];
    // frag kf read = f16 idx kf*512 + lane*8  (16B/lane ds_read_b128, dense).
    __shared__ _Float16 a_hi[1024];
    __shared__ _Float16 a_lo[1024];
    __shared__ float gate_lds[NT * 16 * GPAD];   // [n<208][m] rows of GPAD floats
    __shared__ float xs[TC][BW];                 // transposed: xs[tc][b]

    const int tid  = threadIdx.x;
    const int lane = tid & 63;
    const int wave = tid >> 6;
    const int b0   = blockIdx.x * BW;

    const int nloc = lane & 15;        // N (gate) within tile; also batch m-group
    const int kq   = lane >> 4;        // quad: k0 = kq*8 within K-frag; m-base = kq*4

    // ---- one-time: B fragments (W_hh^T) in f16 hi+lo ----
    // lane holds B[k = kf*32 + kq*8 + j][n = nt*16 + nloc], j=0..7
    f16x8 Bhi[4][2], Blo[4][2];
    int ntile[4];
    for (int i = 0; i < 4; ++i) ntile[i] = wave + 4 * i;   // wave0: 0,4,8,12
    for (int i = 0; i < 4; ++i) {
        int nt = ntile[i];
        for (int kf = 0; kf < 2; ++kf) {
            f16x8 vh, vl;
            #pragma unroll
            for (int j = 0; j < 8; ++j) {
                int n = nt * 16 + nloc;
                int k = kf * 32 + kq * 8 + j;
                float w = (nt < NT && n < 200 && k < H) ? W_hh[n * H + k] : 0.f;
                _Float16 hi = (_Float16)w;
                vh[j] = hi;
                vl[j] = (_Float16)(w - (float)hi);
            }
            Bhi[i][kf] = vh; Blo[i][kf] = vl;
        }
    }

    // ---- one-time: epilogue per-thread constants (unit u = j*16 + b) ----
    float wih[4][4], bias[4][4], wlin[4], c[4], hlast[4];
    int uj[4], ub[4]; bool uact[4];
    for (int r = 0; r < 4; ++r) {
        int u = tid + 256 * r;
        uact[r] = (u < H * BW);            // 800 units
        int j = u >> 4, b = u & 15;
        uj[r] = j; ub[r] = b;
        c[r] = 0.f; hlast[r] = 0.f; wlin[r] = 0.f;
        if (uact[r]) {
            wlin[r] = W_lin[j];
            #pragma unroll
            for (int g_ = 0; g_ < 4; ++g_) {
                wih[r][g_]  = W_ih[j + 50 * g_];
                bias[r][g_] = b_ih[j + 50 * g_] + b_hh[j + 50 * g_];
            }
        }
    }

    // zero A-stage (covers j>=50 zero-pad; h0 = 0)
    for (int idx = tid; idx < 1024; idx += 256) {
        a_hi[idx] = (_Float16)0.f;
        a_lo[idx] = (_Float16)0.f;
    }
    __syncthreads();

    for (int t = 0; t < TT; ++t) {
        const int tc = t & (TC - 1);
        if (tc == 0) {
            // coalesced global read, transposed LDS store; previous step's
            // closing barrier guarantees old xs reads are done.
            int bb = tid & 15, cc = tid >> 4;
            xs[cc][bb] = x[(b0 + bb) * TT + t + cc];
        }

        // ---- MFMA phase: gates[m<16][n<208] = h @ W_hh^T ----
        f16x8 Ah0 = *(const f16x8*)&a_hi[lane * 8];
        f16x8 Ah1 = *(const f16x8*)&a_hi[512 + lane * 8];
        f16x8 Al0 = *(const f16x8*)&a_lo[lane * 8];
        f16x8 Al1 = *(const f16x8*)&a_lo[512 + lane * 8];
        #pragma unroll
        for (int i = 0; i < 4; ++i) {
            int nt = ntile[i];
            if (nt >= NT) break;
            f32x4 acc = {0.f, 0.f, 0.f, 0.f};
            acc = __builtin_amdgcn_mfma_f32_16x16x32_f16(Ah0, Bhi[i][0], acc, 0, 0, 0);
            acc = __builtin_amdgcn_mfma_f32_16x16x32_f16(Ah1, Bhi[i][1], acc, 0, 0, 0);
            acc = __builtin_amdgcn_mfma_f32_16x16x32_f16(Al0, Bhi[i][0], acc, 0, 0, 0);
            acc = __builtin_amdgcn_mfma_f32_16x16x32_f16(Al1, Bhi[i][1], acc, 0, 0, 0);
            acc = __builtin_amdgcn_mfma_f32_16x16x32_f16(Ah0, Blo[i][0], acc, 0, 0, 0);
            acc = __builtin_amdgcn_mfma_f32_16x16x32_f16(Ah1, Blo[i][1], acc, 0, 0, 0);
            // D[m = kq*4 + r][n = nt*16 + nloc] -> gate_lds[n][m], float4 along m
            *(f32x4*)&gate_lds[(nt * 16 + nloc) * GPAD + kq * 4] = acc;
        }
        __syncthreads();   // gates visible; A-frag reads drained

        // ---- epilogue: activations + state update ----
        #pragma unroll
        for (int r = 0; r < 4; ++r) {
            if (!uact[r]) continue;
            int j = uj[r], b = ub[r];
            float xv = xs[tc][b];
            float gi = gate_lds[(j      ) * GPAD + b] + wih[r][0] * xv + bias[r][0];
            float gf = gate_lds[(j +  50) * GPAD + b] + wih[r][1] * xv + bias[r][1];
            float gg = gate_lds[(j + 100) * GPAD + b] + wih[r][2] * xv + bias[r][2];
            float go = gate_lds[(j + 150) * GPAD + b] + wih[r][3] * xv + bias[r][3];
            float i_ = fast_sigmoid(gi);
            float f_ = fast_sigmoid(gf);
            float g_ = fast_tanh(gg);
            float o_ = fast_sigmoid(go);
            c[r] = __builtin_fmaf(f_, c[r], i_ * g_);
            float h = o_ * fast_tanh(c[r]);
            hlast[r] = h;
            _Float16 hh = (_Float16)h;
            _Float16 hl = (_Float16)(h - (float)hh);
            int fi = ((j >> 3) * 16 + b) * 8 + (j & 7);   // [kc][m][e]
            a_hi[fi] = hh;
            a_lo[fi] = hl;
        }
        __syncthreads();   // new h visible; gate_lds safe to overwrite
    }

    // ---- head: out[b] = sum_j W_lin[j]*h[j][b] + b_lin ----
    #pragma unroll
    for (int r = 0; r < 4; ++r)
        if (uact[r]) gate_lds[uj[r] * GPAD + ub[r]] = wlin[r] * hlast[r];
    __syncthreads();
    if (tid < BW) {
        float s = b_lin[0];
        for (int j = 0; j < H; ++j) s += gate_lds[j * GPAD + tid];
        out[b0 + tid] = s;
    }
}

extern "C" void kernel_launch(void* const* d_in, const int* in_sizes, int n_in,
                              void* d_out, int out_size, void* d_ws, size_t ws_size,
                              hipStream_t stream) {
    const float* x     = (const float*)d_in[0];
    const float* W_ih  = (const float*)d_in[1];
    const float* W_hh  = (const float*)d_in[2];
    const float* b_ih  = (const float*)d_in[3];
    const float* b_hh  = (const float*)d_in[4];
    const float* W_lin = (const float*)d_in[5];
    const float* b_lin = (const float*)d_in[6];
    float* out = (float*)d_out;

    dim3 grid(BATCH / BW);   // 128 blocks x 16 batch chains
    dim3 block(256);
    lstm_kernel<<<grid, block, 0, stream>>>(x, W_ih, W_hh, b_ih, b_hh,
                                            W_lin, b_lin, out);
}

// Round 3
// 512.810 us; speedup vs baseline: 2.6680x; 2.1542x over previous
//
#include <hip/hip_runtime.h>

// LSTM B=2048, T=1024, H=50. Round 3: epilogue-in-lane orientation.
//
// D = W' @ h^T per step:  A = W' [200 gate-rows x 64k] (CONSTANT, f16 hi+lo
// in VGPRs, loaded once), B = h^T [64k x 16 batches] (f16, LDS, dbl-buffered).
// Gate rows permuted unit-interleaved: n' = 4*j + g  (g in {i,f,g,o}).
// MFMA 16x16x32 C/D layout: col=lane&15=batch, row=(lane>>4)*4+r = gate row.
// => lane (b=lane&15, kq=lane>>4) of wave t holds ALL 4 gates of unit
//    j=4t+kq, batch b in acc[0..3]. Epilogue is pure per-lane register math;
//    c-state lives in the lane. Only h touches LDS (f16, one b16 write/lane).
// One barrier per step (h double-buffer removes the WAR barrier).
// Block = 832 thr = 13 waves = 13 tiles (52 units: 50 real + 2 zero-pad).
// Grid = 128 (16 batches per block).

#define H     50
#define TT    1024
#define BATCH 2048
#define BW    16
#define NW    13      // waves = tiles
#define JPAD  80      // f16 per h row (160 B = 40 banks; breaks pow2 stride)

typedef float    f32x4 __attribute__((ext_vector_type(4)));
typedef _Float16 f16x8 __attribute__((ext_vector_type(8)));

__device__ __forceinline__ float fast_sigmoid(float x) {
    float e = __builtin_amdgcn_exp2f(-1.4426950408889634f * x);
    return __builtin_amdgcn_rcpf(1.0f + e);
}
__device__ __forceinline__ float fast_tanh(float x) {
    float e = __builtin_amdgcn_exp2f(2.8853900817779268f * x);
    return 1.0f - 2.0f * __builtin_amdgcn_rcpf(e + 1.0f);
}

__global__ __launch_bounds__(832, 1) void lstm_kernel(
    const float* __restrict__ x,      // [B, T]
    const float* __restrict__ W_ih,   // [200]
    const float* __restrict__ W_hh,   // [200, 50]
    const float* __restrict__ b_ih,   // [200]
    const float* __restrict__ b_hh,   // [200]
    const float* __restrict__ W_lin,  // [50]
    const float* __restrict__ b_lin,  // [1]
    float* __restrict__ out)          // [B]
{
    __shared__ _Float16 hbuf[2][BW][JPAD];   // h^T, batch-major rows
    __shared__ float red[NW * 4][BW];        // head reduction scratch

    const int tid  = threadIdx.x;
    const int wave = tid >> 6;     // == tile index 0..12
    const int lane = tid & 63;
    const int L15  = lane & 15;    // A: m-row | B/D: batch b
    const int kq   = lane >> 4;
    const int b0   = blockIdx.x * BW;
    const int tile = wave;

    // ---- A fragments: W' rows in f16 hi+lo (held in VGPRs for all 1024 steps)
    // A[kf] elem e = W'[m = tile*16 + L15][k = kf*32 + kq*8 + e]
    // W'[4j+g][k] = W_hh[g*50 + j][k]
    f16x8 Ahi[2], Alo[2];
    {
        const int m  = tile * 16 + L15;     // permuted gate row 0..207
        const int jm = m >> 2, gm = m & 3;  // unit, gate of this row
        for (int kf = 0; kf < 2; ++kf) {
            f16x8 vh, vl;
            #pragma unroll
            for (int e = 0; e < 8; ++e) {
                int k = kf * 32 + kq * 8 + e;
                float w = (jm < H && k < H) ? W_hh[(gm * H + jm) * H + k] : 0.f;
                _Float16 hi16 = (_Float16)w;
                vh[e] = hi16;
                vl[e] = (_Float16)(w - (float)hi16);
            }
            Ahi[kf] = vh; Alo[kf] = vl;
        }
    }

    // ---- epilogue constants: unit ju = 4*tile + kq, batch b = L15 ----
    const int ju = 4 * tile + kq;
    const bool jact = (ju < H);
    float wih[4], bias[4];
    #pragma unroll
    for (int g = 0; g < 4; ++g) {
        wih[g]  = jact ? W_ih[g * H + ju] : 0.f;
        bias[g] = jact ? (b_ih[g * H + ju] + b_hh[g * H + ju]) : 0.f;
    }
    const float wlin = jact ? W_lin[ju] : 0.f;

    // ---- x prefetch: this lane needs x[b0+L15][t] (L1-broadcast across waves)
    const float* xrow = x + (size_t)(b0 + L15) * TT;
    float4 xcur = *(const float4*)(xrow);        // t = 0..3
    float4 xnxt = *(const float4*)(xrow + 4);    // t = 4..7

    // ---- zero h buffers (h0 = 0, and j >= 52 pad stays 0 forever) ----
    for (int i = tid; i < 2 * BW * JPAD; i += 832)
        ((_Float16*)hbuf)[i] = (_Float16)0.f;

    float c = 0.f, hlast = 0.f;
    __syncthreads();

    for (int t = 0; t < TT; ++t) {
        // B fragments: B[k = kf*32 + kq*8 + e][n = b] = h[k][b]
        const _Float16* hb = &hbuf[t & 1][L15][0];
        f16x8 B0 = *(const f16x8*)(hb + kq * 8);
        f16x8 B1 = *(const f16x8*)(hb + 32 + kq * 8);

        f32x4 acc = {0.f, 0.f, 0.f, 0.f};
        acc = __builtin_amdgcn_mfma_f32_16x16x32_f16(Ahi[0], B0, acc, 0, 0, 0);
        acc = __builtin_amdgcn_mfma_f32_16x16x32_f16(Ahi[1], B1, acc, 0, 0, 0);
        acc = __builtin_amdgcn_mfma_f32_16x16x32_f16(Alo[0], B0, acc, 0, 0, 0);
        acc = __builtin_amdgcn_mfma_f32_16x16x32_f16(Alo[1], B1, acc, 0, 0, 0);

        const float xv = ((const float*)&xcur)[t & 3];
        if ((t & 3) == 3) {            // advance x prefetch (one block ahead)
            xcur = xnxt;
            int off = t + 5; if (off > TT - 4) off = TT - 4;
            xnxt = *(const float4*)(xrow + off);
        }

        // ---- per-lane epilogue: gates i,f,g,o = acc[0..3] ----
        float i_ = fast_sigmoid(acc[0] + __builtin_fmaf(wih[0], xv, bias[0]));
        float f_ = fast_sigmoid(acc[1] + __builtin_fmaf(wih[1], xv, bias[1]));
        float g_ = fast_tanh   (acc[2] + __builtin_fmaf(wih[2], xv, bias[2]));
        float o_ = fast_sigmoid(acc[3] + __builtin_fmaf(wih[3], xv, bias[3]));
        c = __builtin_fmaf(f_, c, i_ * g_);
        float h = o_ * fast_tanh(c);
        hlast = h;
        hbuf[(t + 1) & 1][L15][ju] = (_Float16)h;   // ju<=51 < JPAD; pad rows ok

        __syncthreads();   // new h visible; old buffer's reads long drained
    }

    // ---- head: out[b] = sum_j W_lin[j] * h_T[j][b] + b_lin (fp32 hlast) ----
    red[tile * 4 + kq][L15] = wlin * hlast;
    __syncthreads();
    if (tid < BW) {
        float s = b_lin[0];
        #pragma unroll 4
        for (int r = 0; r < NW * 4; ++r) s += red[r][tid];
        out[b0 + tid] = s;
    }
}

extern "C" void kernel_launch(void* const* d_in, const int* in_sizes, int n_in,
                              void* d_out, int out_size, void* d_ws, size_t ws_size,
                              hipStream_t stream) {
    const float* x     = (const float*)d_in[0];
    const float* W_ih  = (const float*)d_in[1];
    const float* W_hh  = (const float*)d_in[2];
    const float* b_ih  = (const float*)d_in[3];
    const float* b_hh  = (const float*)d_in[4];
    const float* W_lin = (const float*)d_in[5];
    const float* b_lin = (const float*)d_in[6];
    float* out = (float*)d_out;

    dim3 grid(BATCH / BW);    // 128 blocks x 16 batches
    dim3 block(832);          // 13 waves = 13 gate-row tiles
    lstm_kernel<<<grid, block, 0, stream>>>(x, W_ih, W_hh, b_ih, b_hh,
                                            W_lin, b_lin, out);
}